// Round 23
// baseline (160.573 us; speedup 1.0000x reference)
//
#include <hip/hip_runtime.h>
#include <cstdint>
#include <cstddef>

static constexpr int IN_F  = 256;
static constexpr int OUT_F = 128;
#define ALPHA_SLOPE 0.2f
#define NB 256           // blocks for hist/scatter passes
#define BUCK_SH 7        // 128 nodes per bucket
#define CAP 6144         // max edges per bucket staged in LDS

typedef __attribute__((ext_vector_type(8))) short short8;
typedef __attribute__((ext_vector_type(4))) float f32x4;
union ABFrag { uint32_t u[4]; short8 v; };

__device__ __forceinline__ uint32_t pack_bf2(float lo, float hi) {
    uint32_t ul = __float_as_uint(lo), uh = __float_as_uint(hi);
    uint32_t rl = (ul + 0x7fffu + ((ul >> 16) & 1u)) >> 16;
    uint32_t rh = (uh + 0x7fffu + ((uh >> 16) & 1u)) & 0xffff0000u;
    return rl | rh;
}
__device__ __forceinline__ uint32_t cvtpk_bf2(float lo, float hi) {
    uint32_t r;
    asm("v_cvt_pk_bf16_f32 %0, %1, %2" : "=v"(r) : "v"(lo), "v"(hi));
    return r;
}
__device__ __forceinline__ float blo(uint32_t w) { return __uint_as_float(w << 16); }
__device__ __forceinline__ float bhi(uint32_t w) { return __uint_as_float(w & 0xffff0000u); }

#define RL_F(x, l) __uint_as_float(__builtin_amdgcn_readlane(__float_as_uint(x), (l)))
#define RL_I(x, l) __builtin_amdgcn_readlane((x), (l))

__device__ __forceinline__ int edge_at(const void* ei, int idx, int is64) {
    return is64 ? (int)((const long long*)ei)[idx] : ((const int*)ei)[idx];
}

// ---------------------------------------------------------------------------
// K1 fused: blocks 0..63 WtH (swizzled); block 64 waL/waR; 65..320 histogram.
// ---------------------------------------------------------------------------
__global__ __launch_bounds__(256) void prep_hist_kernel(
    const float* __restrict__ W, const float* __restrict__ aL,
    const float* __restrict__ aR, const void* __restrict__ EI,
    int E, int nbuk, uint32_t* __restrict__ WtH,
    float* __restrict__ waL, float* __restrict__ waR, int* __restrict__ C)
{
    if (blockIdx.x < 64) {
        int dd = blockIdx.x * 256 + threadIdx.x;     // 0..16383
        int n  = dd >> 7;
        int kd = (dd & 127) ^ ((n & 7) << 2);
        int k  = kd * 2;
        WtH[dd] = pack_bf2(W[(size_t)k * OUT_F + n], W[(size_t)(k + 1) * OUT_F + n]);
        return;
    }
    if (blockIdx.x == 64) {
        int k = threadIdx.x;
        const float* wr = W + (size_t)k * OUT_F;
        float sl = 0.f, sr = 0.f;
        for (int j = 0; j < OUT_F; j++) {
            float wv = wr[j];
            sl = fmaf(wv, aL[j], sl);
            sr = fmaf(wv, aR[j], sr);
        }
        waL[k] = sl; waR[k] = sr;
        return;
    }
    __shared__ int h[800];
    __shared__ int det;
    if (threadIdx.x == 0) det = 0;
    for (int b = threadIdx.x; b < nbuk; b += 256) h[b] = 0;
    __syncthreads();
    {
        const unsigned* eu = (const unsigned*)EI;
        int nz = 0;
        for (int i = threadIdx.x; i < 1024; i += 256)
            if (eu[2 * i + 1] != 0u) nz++;
        if (nz) atomicAdd(&det, 1);
    }
    __syncthreads();
    const int is64 = (det == 0);
    const int bid = blockIdx.x - 65;
    int chunk = (E + NB - 1) / NB;
    int start = bid * chunk;
    int end = min(start + chunk, E);
    for (int i = start + threadIdx.x; i < end; i += 256) {
        int s = edge_at(EI, i, is64);
        atomicAdd(&h[s >> BUCK_SH], 1);
    }
    __syncthreads();
    for (int b = threadIdx.x; b < nbuk; b += 256)
        C[b * NB + bid] = h[b];
}

__global__ __launch_bounds__(256) void scan1_kernel(const int* __restrict__ counts,
                                                    int* __restrict__ offsets,
                                                    int* __restrict__ partials, int N) {
    __shared__ int wt[4];
    int gid = blockIdx.x * 256 + threadIdx.x;
    const int lane = threadIdx.x & 63, wave = threadIdx.x >> 6;
    int c = (gid < N) ? counts[gid] : 0;
    int incl = c;
#pragma unroll
    for (int o = 1; o < 64; o <<= 1) {
        int v = __shfl_up(incl, o);
        if (lane >= o) incl += v;
    }
    if (lane == 63) wt[wave] = incl;
    __syncthreads();
    int woff = 0;
    for (int w = 0; w < wave; w++) woff += wt[w];
    if (gid < N) offsets[gid] = woff + incl - c;
    if (threadIdx.x == 0) partials[blockIdx.x] = wt[0] + wt[1] + wt[2] + wt[3];
}

__global__ __launch_bounds__(256) void scan2_kernel(int* data, int n) {
    __shared__ int wt[4];
    __shared__ int carry_s;
    if (threadIdx.x == 0) carry_s = 0;
    __syncthreads();
    const int lane = threadIdx.x & 63, wave = threadIdx.x >> 6;
    for (int base = 0; base < n; base += 256) {
        int i = base + threadIdx.x;
        int c = (i < n) ? data[i] : 0;
        int incl = c;
#pragma unroll
        for (int o = 1; o < 64; o <<= 1) {
            int v = __shfl_up(incl, o);
            if (lane >= o) incl += v;
        }
        if (lane == 63) wt[wave] = incl;
        __syncthreads();
        int woff = 0;
        for (int w = 0; w < wave; w++) woff += wt[w];
        int total = wt[0] + wt[1] + wt[2] + wt[3];
        int carry = carry_s;
        __syncthreads();
        if (i < n) data[i] = carry + woff + incl - c;
        if (threadIdx.x == 0) carry_s = carry + total;
        __syncthreads();
    }
}

// ---------------------------------------------------------------------------
// scatter: STANDALONE (un-fused from gemm). 256 thr x NB blocks.
// ---------------------------------------------------------------------------
__global__ __launch_bounds__(256) void scatter_kernel(
    const void* __restrict__ EI, int E, int nbuk,
    const int* __restrict__ Cx, const int* __restrict__ T,
    uint32_t* __restrict__ entries)
{
    __shared__ int cur[800];
    __shared__ int det;
    const int tid = threadIdx.x;
    if (tid == 0) det = 0;
    for (int b = tid; b < nbuk; b += 256) cur[b] = 0;
    __syncthreads();
    {
        const unsigned* eu = (const unsigned*)EI;
        int nz = 0;
        for (int i = tid; i < 1024; i += 256)
            if (eu[2 * i + 1] != 0u) nz++;
        if (nz) atomicAdd(&det, 1);
    }
    __syncthreads();
    const int is64 = (det == 0);
    const int bid = blockIdx.x;
    int chunk = (E + NB - 1) / NB;
    int start = bid * chunk;
    int end = min(start + chunk, E);
    for (int i = start + tid; i < end; i += 256) {
        int s = edge_at(EI, i, is64);
        int d = edge_at(EI, E + i, is64);
        int b = s >> BUCK_SH;
        int pos = T[b] + Cx[b * NB + bid] + atomicAdd(&cur[b], 1);
        entries[pos] = ((uint32_t)(s & 127) << 17) | (uint32_t)d;
    }
}

// ---------------------------------------------------------------------------
// gemm: STANDALONE (round-11 body verbatim — the configuration that ran
// <=70us before fusion clamped it to 64 VGPR + spills). Plain LDS staging,
// plain xv[16] full-row prefetch, no inline-asm loads, no launch-bounds cap.
// ---------------------------------------------------------------------------
__global__ __launch_bounds__(512) void gemm_kernel(
    const float* __restrict__ X, const uint32_t* __restrict__ WtH,
    const float* __restrict__ waL, const float* __restrict__ waR,
    uint32_t* __restrict__ Whh, float* __restrict__ el, float* __restrict__ er,
    int M)
{
    __shared__ uint32_t ldsW[16384];             // 64 KB: W^T bf16 swizzled
    const int tid = threadIdx.x;
    const int w = tid >> 6, l = tid & 63;
    const int c = l & 15, kg = l >> 4;
    const int swz = (c & 7) << 2;

    {   // stage WtH -> LDS, linear (pre-swizzled in global)
        const uint4* src = (const uint4*)WtH;
        uint4* dst = (uint4*)ldsW;
#pragma unroll
        for (int i = 0; i < 8; i++)
            dst[tid + i * 512] = src[tid + i * 512];
    }

    const int bm = blockIdx.x * 128;
    const int myrow = w * 16 + c;
    const int grow = min(bm + myrow, M - 1);     // clamp: benign dup reads
    const bool rv = (bm + myrow) < M;
    const float* xp = X + (size_t)grow * IN_F + kg * 8;

    // full-row prefetch: 16 independent dwordx4 loads in flight
    float4 xv[16];
#pragma unroll
    for (int ks = 0; ks < 8; ks++) {
        xv[2 * ks]     = *(const float4*)(xp + ks * 32);
        xv[2 * ks + 1] = *(const float4*)(xp + ks * 32 + 4);
    }

    f32x4 acc[8];
#pragma unroll
    for (int j = 0; j < 8; j++) acc[j] = (f32x4){0.f, 0.f, 0.f, 0.f};
    float sl = 0.f, sr = 0.f;

    __syncthreads();                             // W^T staged

#pragma unroll
    for (int ks = 0; ks < 8; ks++) {
        float4 xa = xv[2 * ks], xb = xv[2 * ks + 1];
        const float* wlp = waL + ks * 32 + kg * 8;
        const float* wrp = waR + ks * 32 + kg * 8;
        float4 l0 = *(const float4*)wlp, l1 = *(const float4*)(wlp + 4);
        float4 r0 = *(const float4*)wrp, r1 = *(const float4*)(wrp + 4);
        sl = fmaf(xa.x, l0.x, sl); sl = fmaf(xa.y, l0.y, sl);
        sl = fmaf(xa.z, l0.z, sl); sl = fmaf(xa.w, l0.w, sl);
        sl = fmaf(xb.x, l1.x, sl); sl = fmaf(xb.y, l1.y, sl);
        sl = fmaf(xb.z, l1.z, sl); sl = fmaf(xb.w, l1.w, sl);
        sr = fmaf(xa.x, r0.x, sr); sr = fmaf(xa.y, r0.y, sr);
        sr = fmaf(xa.z, r0.z, sr); sr = fmaf(xa.w, r0.w, sr);
        sr = fmaf(xb.x, r1.x, sr); sr = fmaf(xb.y, r1.y, sr);
        sr = fmaf(xb.z, r1.z, sr); sr = fmaf(xb.w, r1.w, sr);
        ABFrag a;
        a.u[0] = cvtpk_bf2(xa.x, xa.y); a.u[1] = cvtpk_bf2(xa.z, xa.w);
        a.u[2] = cvtpk_bf2(xb.x, xb.y); a.u[3] = cvtpk_bf2(xb.z, xb.w);
        const int kd = ks * 16 + kg * 4;
#pragma unroll
        for (int j = 0; j < 8; j++) {
            const int col = j * 16 + c;
            ABFrag b;
            *(uint4*)b.u = *(const uint4*)&ldsW[col * 128 + (kd ^ swz)];
            acc[j] = __builtin_amdgcn_mfma_f32_16x16x32_bf16(a.v, b.v, acc[j], 0, 0, 0);
        }
    }

    sl += __shfl_xor(sl, 16); sl += __shfl_xor(sl, 32);
    sr += __shfl_xor(sr, 16); sr += __shfl_xor(sr, 32);
    if (rv && kg == 0) { el[bm + myrow] = sl; er[bm + myrow] = sr; }

    __syncthreads();                             // done with W^T; reuse as scratch
    float* sc = (float*)ldsW + w * 2048;
#pragma unroll
    for (int j = 0; j < 8; j++)
#pragma unroll
        for (int r = 0; r < 4; r++)
            sc[(kg * 4 + r) * 128 + j * 16 + c] = acc[j][r];
    __syncthreads();
#pragma unroll
    for (int m = 0; m < 16; m++) {
        float2 p = *(const float2*)&sc[m * 128 + 2 * l];
        int orow = bm + w * 16 + m;
        if (orow < M) Whh[(size_t)orow * 64 + l] = cvtpk_bf2(p.x, p.y);
    }
}

// ---------------------------------------------------------------------------
// bucket: one block per bucket — in-LDS counting sort, coalesced CSR output.
// ---------------------------------------------------------------------------
__global__ __launch_bounds__(256) void bucket_kernel(const uint32_t* __restrict__ entries,
                                                     const int* __restrict__ T,
                                                     int E, int N, int nbuk,
                                                     int* __restrict__ offsets,
                                                     int* __restrict__ edge_dst) {
    __shared__ uint32_t ent[CAP];
    __shared__ int outD[CAP];
    __shared__ int cnt[128], pre[128], cur[128];
    __shared__ int wt4[2];
    const int b = blockIdx.x;
    const int tid = threadIdx.x;
    const int base = T[b];
    const int cend = (b + 1 < nbuk) ? T[b + 1] : E;
    int count = cend - base;
    if (count > CAP) count = CAP;

    if (tid < 128) { cnt[tid] = 0; cur[tid] = 0; }
    __syncthreads();
    for (int k = tid; k < count; k += 256) {
        uint32_t e = entries[base + k];
        ent[k] = e;
        atomicAdd(&cnt[e >> 17], 1);
    }
    __syncthreads();
    {
        const int lane = tid & 63, w = tid >> 6;
        int c = (tid < 128) ? cnt[tid] : 0;
        int incl = c;
#pragma unroll
        for (int o = 1; o < 64; o <<= 1) {
            int v = __shfl_up(incl, o);
            if (lane >= o) incl += v;
        }
        if (w == 0 && lane == 63) wt4[0] = incl;
        __syncthreads();
        if (tid < 128) pre[tid] = ((w == 1) ? wt4[0] : 0) + incl - c;
        __syncthreads();
    }
    const int node0 = b << BUCK_SH;
    const int nnode = min(128, N - node0);
    if (tid < nnode) offsets[node0 + tid] = base + pre[tid];
    if (b == nbuk - 1 && tid == 0) offsets[N] = E;
    for (int k = tid; k < count; k += 256) {
        uint32_t e = ent[k];
        int sl = e >> 17;
        int p = pre[sl] + atomicAdd(&cur[sl], 1);
        outD[p] = (int)(e & 0x1FFFFu);
    }
    __syncthreads();
    for (int k = tid; k < count; k += 256)
        edge_dst[base + k] = outD[k];
}

// ---------------------------------------------------------------------------
// node: single-pass register softmax + PV, 4-deep gather (best measured).
// ---------------------------------------------------------------------------
__global__ __launch_bounds__(256) void node_kernel(const int* __restrict__ offsets,
                                                   const int* __restrict__ edge_dst,
                                                   const float* __restrict__ el,
                                                   const float* __restrict__ er,
                                                   const uint32_t* __restrict__ WhH,
                                                   float* __restrict__ out, int N) {
    int node = blockIdx.x * 4 + (threadIdx.x >> 6);
    int lane = threadIdx.x & 63;
    if (node >= N) return;
    int s0  = offsets[node];
    int deg = offsets[node + 1] - s0;
    float eli = el[node];

    if (deg <= 64) {
        int dj = 0;
        float e = -3.402823466e38f;
        if (lane < deg) {
            dj = edge_dst[s0 + lane];
            float t = eli + er[dj];
            e = t > 0.f ? t : ALPHA_SLOPE * t;
        }
        float m = e;
#pragma unroll
        for (int o = 32; o > 0; o >>= 1) m = fmaxf(m, __shfl_xor(m, o));
        float ex = (lane < deg) ? expf(e - m) : 0.f;
        float ssum = ex;
#pragma unroll
        for (int o = 32; o > 0; o >>= 1) ssum += __shfl_xor(ssum, o);
        float p = ex / (ssum + 1e-9f);

        const int g = lane >> 4, q = lane & 15;
        float a0 = 0.f, a1 = 0.f, a2 = 0.f, a3 = 0.f;
        float a4 = 0.f, a5 = 0.f, a6 = 0.f, a7 = 0.f;
        int rounds = (deg + 3) >> 2;
        int r = 0;
        for (; r + 4 <= rounds; r += 4) {
            int i0 = (r << 2) + g, i1 = i0 + 4, i2 = i0 + 8, i3 = i0 + 12;
            float p0 = __shfl(p, i0), p1 = __shfl(p, i1);
            float p2 = __shfl(p, i2), p3 = __shfl(p, i3);
            int   e0 = __shfl(dj, i0), e1 = __shfl(dj, i1);
            int   e2 = __shfl(dj, i2), e3 = __shfl(dj, i3);
            uint4 w0 = *(const uint4*)&WhH[(size_t)e0 * 64 + q * 4];
            uint4 w1 = *(const uint4*)&WhH[(size_t)e1 * 64 + q * 4];
            uint4 w2 = *(const uint4*)&WhH[(size_t)e2 * 64 + q * 4];
            uint4 w3 = *(const uint4*)&WhH[(size_t)e3 * 64 + q * 4];
            a0 = fmaf(p0, blo(w0.x), a0); a1 = fmaf(p0, bhi(w0.x), a1);
            a2 = fmaf(p0, blo(w0.y), a2); a3 = fmaf(p0, bhi(w0.y), a3);
            a4 = fmaf(p0, blo(w0.z), a4); a5 = fmaf(p0, bhi(w0.z), a5);
            a6 = fmaf(p0, blo(w0.w), a6); a7 = fmaf(p0, bhi(w0.w), a7);
            a0 = fmaf(p1, blo(w1.x), a0); a1 = fmaf(p1, bhi(w1.x), a1);
            a2 = fmaf(p1, blo(w1.y), a2); a3 = fmaf(p1, bhi(w1.y), a3);
            a4 = fmaf(p1, blo(w1.z), a4); a5 = fmaf(p1, bhi(w1.z), a5);
            a6 = fmaf(p1, blo(w1.w), a6); a7 = fmaf(p1, bhi(w1.w), a7);
            a0 = fmaf(p2, blo(w2.x), a0); a1 = fmaf(p2, bhi(w2.x), a1);
            a2 = fmaf(p2, blo(w2.y), a2); a3 = fmaf(p2, bhi(w2.y), a3);
            a4 = fmaf(p2, blo(w2.z), a4); a5 = fmaf(p2, bhi(w2.z), a5);
            a6 = fmaf(p2, blo(w2.w), a6); a7 = fmaf(p2, bhi(w2.w), a7);
            a0 = fmaf(p3, blo(w3.x), a0); a1 = fmaf(p3, bhi(w3.x), a1);
            a2 = fmaf(p3, blo(w3.y), a2); a3 = fmaf(p3, bhi(w3.y), a3);
            a4 = fmaf(p3, blo(w3.z), a4); a5 = fmaf(p3, bhi(w3.z), a5);
            a6 = fmaf(p3, blo(w3.w), a6); a7 = fmaf(p3, bhi(w3.w), a7);
        }
        for (; r + 2 <= rounds; r += 2) {
            int i0 = (r << 2) + g, i1 = i0 + 4;
            float p0 = __shfl(p, i0), p1 = __shfl(p, i1);
            int   e0 = __shfl(dj, i0), e1 = __shfl(dj, i1);
            uint4 w0 = *(const uint4*)&WhH[(size_t)e0 * 64 + q * 4];
            uint4 w1 = *(const uint4*)&WhH[(size_t)e1 * 64 + q * 4];
            a0 = fmaf(p0, blo(w0.x), a0); a1 = fmaf(p0, bhi(w0.x), a1);
            a2 = fmaf(p0, blo(w0.y), a2); a3 = fmaf(p0, bhi(w0.y), a3);
            a4 = fmaf(p0, blo(w0.z), a4); a5 = fmaf(p0, bhi(w0.z), a5);
            a6 = fmaf(p0, blo(w0.w), a6); a7 = fmaf(p0, bhi(w0.w), a7);
            a0 = fmaf(p1, blo(w1.x), a0); a1 = fmaf(p1, bhi(w1.x), a1);
            a2 = fmaf(p1, blo(w1.y), a2); a3 = fmaf(p1, bhi(w1.y), a3);
            a4 = fmaf(p1, blo(w1.z), a4); a5 = fmaf(p1, bhi(w1.z), a5);
            a6 = fmaf(p1, blo(w1.w), a6); a7 = fmaf(p1, bhi(w1.w), a7);
        }
        if (r < rounds) {
            int i0 = (r << 2) + g;
            float p0 = __shfl(p, i0);
            int   e0 = __shfl(dj, i0);
            uint4 w0 = *(const uint4*)&WhH[(size_t)e0 * 64 + q * 4];
            a0 = fmaf(p0, blo(w0.x), a0); a1 = fmaf(p0, bhi(w0.x), a1);
            a2 = fmaf(p0, blo(w0.y), a2); a3 = fmaf(p0, bhi(w0.y), a3);
            a4 = fmaf(p0, blo(w0.z), a4); a5 = fmaf(p0, bhi(w0.z), a5);
            a6 = fmaf(p0, blo(w0.w), a6); a7 = fmaf(p0, bhi(w0.w), a7);
        }
#pragma unroll
        for (int o = 16; o <= 32; o <<= 1) {
            a0 += __shfl_xor(a0, o); a1 += __shfl_xor(a1, o);
            a2 += __shfl_xor(a2, o); a3 += __shfl_xor(a3, o);
            a4 += __shfl_xor(a4, o); a5 += __shfl_xor(a5, o);
            a6 += __shfl_xor(a6, o); a7 += __shfl_xor(a7, o);
        }
        if (g == 0) {
            float4 o0 = make_float4(fmaxf(a0, 0.f), fmaxf(a1, 0.f),
                                    fmaxf(a2, 0.f), fmaxf(a3, 0.f));
            float4 o1 = make_float4(fmaxf(a4, 0.f), fmaxf(a5, 0.f),
                                    fmaxf(a6, 0.f), fmaxf(a7, 0.f));
            float* op = out + (size_t)node * OUT_F + q * 8;
            *(float4*)op = o0;
            *(float4*)(op + 4) = o1;
        }
        return;
    }

    // slow path (deg > 64)
    float m = -3.402823466e38f;
    for (int j = lane; j < deg; j += 64) {
        float e = eli + er[edge_dst[s0 + j]];
        e = e > 0.f ? e : ALPHA_SLOPE * e;
        m = fmaxf(m, e);
    }
#pragma unroll
    for (int o = 32; o > 0; o >>= 1) m = fmaxf(m, __shfl_xor(m, o));

    float ssum = 0.f;
    for (int j = lane; j < deg; j += 64) {
        float e = eli + er[edge_dst[s0 + j]];
        e = e > 0.f ? e : ALPHA_SLOPE * e;
        ssum += expf(e - m);
    }
#pragma unroll
    for (int o = 32; o > 0; o >>= 1) ssum += __shfl_xor(ssum, o);
    float inv = 1.f / (ssum + 1e-9f);

    float acc0 = 0.f, acc1 = 0.f;
    for (int base = 0; base < deg; base += 64) {
        int j = base + lane;
        float p = 0.f;
        int d = 0;
        if (j < deg) {
            d = edge_dst[s0 + j];
            float e = eli + er[d];
            e = e > 0.f ? e : ALPHA_SLOPE * e;
            p = expf(e - m) * inv;
        }
        int cnt = min(64, deg - base);
        int t = 0;
        for (; t + 8 <= cnt; t += 8) {
            float b0 = RL_F(p, t + 0), b1 = RL_F(p, t + 1);
            float b2 = RL_F(p, t + 2), b3 = RL_F(p, t + 3);
            float b4 = RL_F(p, t + 4), b5 = RL_F(p, t + 5);
            float b6 = RL_F(p, t + 6), b7 = RL_F(p, t + 7);
            int   d0 = RL_I(d, t + 0), d1 = RL_I(d, t + 1);
            int   d2 = RL_I(d, t + 2), d3 = RL_I(d, t + 3);
            int   d4 = RL_I(d, t + 4), d5 = RL_I(d, t + 5);
            int   d6 = RL_I(d, t + 6), d7 = RL_I(d, t + 7);
            uint32_t w0 = WhH[(size_t)d0 * 64 + lane];
            uint32_t w1 = WhH[(size_t)d1 * 64 + lane];
            uint32_t w2 = WhH[(size_t)d2 * 64 + lane];
            uint32_t w3 = WhH[(size_t)d3 * 64 + lane];
            uint32_t w4 = WhH[(size_t)d4 * 64 + lane];
            uint32_t w5 = WhH[(size_t)d5 * 64 + lane];
            uint32_t w6 = WhH[(size_t)d6 * 64 + lane];
            uint32_t w7 = WhH[(size_t)d7 * 64 + lane];
            acc0 = fmaf(b0, blo(w0), acc0); acc1 = fmaf(b0, bhi(w0), acc1);
            acc0 = fmaf(b1, blo(w1), acc0); acc1 = fmaf(b1, bhi(w1), acc1);
            acc0 = fmaf(b2, blo(w2), acc0); acc1 = fmaf(b2, bhi(w2), acc1);
            acc0 = fmaf(b3, blo(w3), acc0); acc1 = fmaf(b3, bhi(w3), acc1);
            acc0 = fmaf(b4, blo(w4), acc0); acc1 = fmaf(b4, bhi(w4), acc1);
            acc0 = fmaf(b5, blo(w5), acc0); acc1 = fmaf(b5, bhi(w5), acc1);
            acc0 = fmaf(b6, blo(w6), acc0); acc1 = fmaf(b6, bhi(w6), acc1);
            acc0 = fmaf(b7, blo(w7), acc0); acc1 = fmaf(b7, bhi(w7), acc1);
        }
        for (; t < cnt; ++t) {
            float a = RL_F(p, t);
            int  dd = RL_I(d, t);
            uint32_t wv = WhH[(size_t)dd * 64 + lane];
            acc0 = fmaf(a, blo(wv), acc0);
            acc1 = fmaf(a, bhi(wv), acc1);
        }
    }
    out[(size_t)node * OUT_F + 2 * lane]     = fmaxf(acc0, 0.f);
    out[(size_t)node * OUT_F + 2 * lane + 1] = fmaxf(acc1, 0.f);
}

// ---------------------------------------------------------------------------
extern "C" void kernel_launch(void* const* d_in, const int* in_sizes, int n_in,
                              void* d_out, int out_size, void* d_ws, size_t ws_size,
                              hipStream_t stream) {
    (void)n_in; (void)out_size; (void)ws_size;
    const float* X  = (const float*)d_in[0];
    const void*  EI = d_in[1];
    const float* W  = (const float*)d_in[2];
    const float* aL = (const float*)d_in[3];
    const float* aR = (const float*)d_in[4];
    float* out = (float*)d_out;
    const int N = in_sizes[0] / IN_F;
    const int E = in_sizes[1] / 2;
    const int nbuk = (N + 127) >> BUCK_SH;       // 782 for N=100000
    const int GB = (N + 127) / 128;              // gemm blocks

    char* ws = (char*)d_ws;
    float*    waL      = (float*)(ws + 256);            // 256 f32
    float*    waR      = waL + 256;                     // 256 f32
    uint32_t* WtH      = (uint32_t*)(waR + 256);        // 16384 dwords (64 KB)
    uint32_t* Whh      = WtH + 16384;                   // N*64 dwords
    float*    el       = (float*)(Whh + (size_t)N * 64);
    float*    er       = el + N;                        // N
    int*      T        = (int*)(er + N);                // nbuk (pad 1024)
    int*      C        = T + 1024;                      // nbuk*NB
    int*      Cx       = C + (size_t)nbuk * NB;         // nbuk*NB
    int*      offsets  = Cx + (size_t)nbuk * NB;        // N+1
    uint32_t* entries  = (uint32_t*)(offsets + (N + 1)); // E
    int*      edge_dst = (int*)(entries + E);           // E

    prep_hist_kernel<<<65 + NB, 256, 0, stream>>>(W, aL, aR, EI, E, nbuk,
                                                  WtH, waL, waR, C);
    scan1_kernel<<<nbuk, 256, 0, stream>>>(C, Cx, T, nbuk * NB);
    scan2_kernel<<<1, 256, 0, stream>>>(T, nbuk);
    scatter_kernel<<<NB, 256, 0, stream>>>(EI, E, nbuk, Cx, T, entries);
    gemm_kernel<<<GB, 512, 0, stream>>>(X, WtH, waL, waR, Whh, el, er, N);
    bucket_kernel<<<nbuk, 256, 0, stream>>>(entries, T, E, N, nbuk, offsets, edge_dst);
    node_kernel<<<(N + 3) / 4, 256, 0, stream>>>(offsets, edge_dst, el, er, Whh, out, N);
}

// Round 24
// 150.796 us; speedup vs baseline: 1.0648x; 1.0648x over previous
//
#include <hip/hip_runtime.h>
#include <cstdint>
#include <cstddef>

static constexpr int IN_F  = 256;
static constexpr int OUT_F = 128;
#define ALPHA_SLOPE 0.2f
#define NB 256           // scatter/hist chunks
#define BUCK_SH 7        // 128 nodes per bucket
#define CAP 6144         // max edges per bucket staged in LDS

typedef __attribute__((ext_vector_type(8))) short short8;
typedef __attribute__((ext_vector_type(4))) float f32x4;
union ABFrag { uint32_t u[4]; short8 v; };

__device__ __forceinline__ uint32_t pack_bf2(float lo, float hi) {
    uint32_t ul = __float_as_uint(lo), uh = __float_as_uint(hi);
    uint32_t rl = (ul + 0x7fffu + ((ul >> 16) & 1u)) >> 16;
    uint32_t rh = (uh + 0x7fffu + ((uh >> 16) & 1u)) & 0xffff0000u;
    return rl | rh;
}
__device__ __forceinline__ uint32_t cvtpk_bf2(float lo, float hi) {
    uint32_t r;
    asm("v_cvt_pk_bf16_f32 %0, %1, %2" : "=v"(r) : "v"(lo), "v"(hi));
    return r;
}
__device__ __forceinline__ float blo(uint32_t w) { return __uint_as_float(w << 16); }
__device__ __forceinline__ float bhi(uint32_t w) { return __uint_as_float(w & 0xffff0000u); }

#define RL_F(x, l) __uint_as_float(__builtin_amdgcn_readlane(__float_as_uint(x), (l)))
#define RL_I(x, l) __builtin_amdgcn_readlane((x), (l))

__device__ __forceinline__ int edge_at(const void* ei, int idx, int is64) {
    return is64 ? (int)((const long long*)ei)[idx] : ((const int*)ei)[idx];
}

// ---------------------------------------------------------------------------
// K1 fused: blocks 0..63 WtH (swizzled); block 64 waL/waR; 65..320 histogram.
// ---------------------------------------------------------------------------
__global__ __launch_bounds__(256) void prep_hist_kernel(
    const float* __restrict__ W, const float* __restrict__ aL,
    const float* __restrict__ aR, const void* __restrict__ EI,
    int E, int nbuk, uint32_t* __restrict__ WtH,
    float* __restrict__ waL, float* __restrict__ waR, int* __restrict__ C)
{
    if (blockIdx.x < 64) {
        int dd = blockIdx.x * 256 + threadIdx.x;     // 0..16383
        int n  = dd >> 7;
        int kd = (dd & 127) ^ ((n & 7) << 2);
        int k  = kd * 2;
        WtH[dd] = pack_bf2(W[(size_t)k * OUT_F + n], W[(size_t)(k + 1) * OUT_F + n]);
        return;
    }
    if (blockIdx.x == 64) {
        int k = threadIdx.x;
        const float* wr = W + (size_t)k * OUT_F;
        float sl = 0.f, sr = 0.f;
        for (int j = 0; j < OUT_F; j++) {
            float wv = wr[j];
            sl = fmaf(wv, aL[j], sl);
            sr = fmaf(wv, aR[j], sr);
        }
        waL[k] = sl; waR[k] = sr;
        return;
    }
    __shared__ int h[800];
    __shared__ int det;
    if (threadIdx.x == 0) det = 0;
    for (int b = threadIdx.x; b < nbuk; b += 256) h[b] = 0;
    __syncthreads();
    {
        const unsigned* eu = (const unsigned*)EI;
        int nz = 0;
        for (int i = threadIdx.x; i < 1024; i += 256)
            if (eu[2 * i + 1] != 0u) nz++;
        if (nz) atomicAdd(&det, 1);
    }
    __syncthreads();
    const int is64 = (det == 0);
    const int bid = blockIdx.x - 65;
    int chunk = (E + NB - 1) / NB;
    int start = bid * chunk;
    int end = min(start + chunk, E);
    for (int i = start + threadIdx.x; i < end; i += 256) {
        int s = edge_at(EI, i, is64);
        atomicAdd(&h[s >> BUCK_SH], 1);
    }
    __syncthreads();
    for (int b = threadIdx.x; b < nbuk; b += 256)
        C[b * NB + bid] = h[b];
}

__global__ __launch_bounds__(256) void scan1_kernel(const int* __restrict__ counts,
                                                    int* __restrict__ offsets,
                                                    int* __restrict__ partials, int N) {
    __shared__ int wt[4];
    int gid = blockIdx.x * 256 + threadIdx.x;
    const int lane = threadIdx.x & 63, wave = threadIdx.x >> 6;
    int c = (gid < N) ? counts[gid] : 0;
    int incl = c;
#pragma unroll
    for (int o = 1; o < 64; o <<= 1) {
        int v = __shfl_up(incl, o);
        if (lane >= o) incl += v;
    }
    if (lane == 63) wt[wave] = incl;
    __syncthreads();
    int woff = 0;
    for (int w = 0; w < wave; w++) woff += wt[w];
    if (gid < N) offsets[gid] = woff + incl - c;
    if (threadIdx.x == 0) partials[blockIdx.x] = wt[0] + wt[1] + wt[2] + wt[3];
}

__global__ __launch_bounds__(256) void scan2_kernel(int* data, int n) {
    __shared__ int wt[4];
    __shared__ int carry_s;
    if (threadIdx.x == 0) carry_s = 0;
    __syncthreads();
    const int lane = threadIdx.x & 63, wave = threadIdx.x >> 6;
    for (int base = 0; base < n; base += 256) {
        int i = base + threadIdx.x;
        int c = (i < n) ? data[i] : 0;
        int incl = c;
#pragma unroll
        for (int o = 1; o < 64; o <<= 1) {
            int v = __shfl_up(incl, o);
            if (lane >= o) incl += v;
        }
        if (lane == 63) wt[wave] = incl;
        __syncthreads();
        int woff = 0;
        for (int w = 0; w < wave; w++) woff += wt[w];
        int total = wt[0] + wt[1] + wt[2] + wt[3];
        int carry = carry_s;
        __syncthreads();
        if (i < n) data[i] = carry + woff + incl - c;
        if (threadIdx.x == 0) carry_s = carry + total;
        __syncthreads();
    }
}

// ---------------------------------------------------------------------------
// gemm + piggybacked scatter: all GB blocks run the fast unfused gemm body
// (r23, <71us); blocks 0..NB-1 ALSO process their scatter chunk afterwards.
// No dedicated scatter blocks wasting 71KB-LDS CU slots; scatter tails of
// early blocks overlap gemm of later blocks. LDS = 64KB W + 3.2KB cur.
// ---------------------------------------------------------------------------
__global__ __launch_bounds__(512) void gemm_scatter_kernel(
    const float* __restrict__ X, const uint32_t* __restrict__ WtH,
    const float* __restrict__ waL, const float* __restrict__ waR,
    uint32_t* __restrict__ Whh, float* __restrict__ el, float* __restrict__ er,
    int M, const void* __restrict__ EI, int E, int nbuk,
    const int* __restrict__ Cx, const int* __restrict__ T,
    uint32_t* __restrict__ entries)
{
    __shared__ uint32_t ldsW[16384];             // 64 KB: W^T bf16 swizzled
    __shared__ int cur[800];
    __shared__ int det;
    const int tid = threadIdx.x;
    const int w = tid >> 6, l = tid & 63;
    const int c = l & 15, kg = l >> 4;
    const int swz = (c & 7) << 2;

    {   // stage WtH -> LDS, linear (pre-swizzled in global)
        const uint4* src = (const uint4*)WtH;
        uint4* dst = (uint4*)ldsW;
#pragma unroll
        for (int i = 0; i < 8; i++)
            dst[tid + i * 512] = src[tid + i * 512];
    }

    const int bm = blockIdx.x * 128;
    const int myrow = w * 16 + c;
    const int grow = min(bm + myrow, M - 1);     // clamp: benign dup reads
    const bool rv = (bm + myrow) < M;
    const float* xp = X + (size_t)grow * IN_F + kg * 8;

    // full-row prefetch: 16 independent dwordx4 loads in flight
    float4 xv[16];
#pragma unroll
    for (int ks = 0; ks < 8; ks++) {
        xv[2 * ks]     = *(const float4*)(xp + ks * 32);
        xv[2 * ks + 1] = *(const float4*)(xp + ks * 32 + 4);
    }

    f32x4 acc[8];
#pragma unroll
    for (int j = 0; j < 8; j++) acc[j] = (f32x4){0.f, 0.f, 0.f, 0.f};
    float sl = 0.f, sr = 0.f;

    __syncthreads();                             // W^T staged

#pragma unroll
    for (int ks = 0; ks < 8; ks++) {
        float4 xa = xv[2 * ks], xb = xv[2 * ks + 1];
        const float* wlp = waL + ks * 32 + kg * 8;
        const float* wrp = waR + ks * 32 + kg * 8;
        float4 l0 = *(const float4*)wlp, l1 = *(const float4*)(wlp + 4);
        float4 r0 = *(const float4*)wrp, r1 = *(const float4*)(wrp + 4);
        sl = fmaf(xa.x, l0.x, sl); sl = fmaf(xa.y, l0.y, sl);
        sl = fmaf(xa.z, l0.z, sl); sl = fmaf(xa.w, l0.w, sl);
        sl = fmaf(xb.x, l1.x, sl); sl = fmaf(xb.y, l1.y, sl);
        sl = fmaf(xb.z, l1.z, sl); sl = fmaf(xb.w, l1.w, sl);
        sr = fmaf(xa.x, r0.x, sr); sr = fmaf(xa.y, r0.y, sr);
        sr = fmaf(xa.z, r0.z, sr); sr = fmaf(xa.w, r0.w, sr);
        sr = fmaf(xb.x, r1.x, sr); sr = fmaf(xb.y, r1.y, sr);
        sr = fmaf(xb.z, r1.z, sr); sr = fmaf(xb.w, r1.w, sr);
        ABFrag a;
        a.u[0] = cvtpk_bf2(xa.x, xa.y); a.u[1] = cvtpk_bf2(xa.z, xa.w);
        a.u[2] = cvtpk_bf2(xb.x, xb.y); a.u[3] = cvtpk_bf2(xb.z, xb.w);
        const int kd = ks * 16 + kg * 4;
#pragma unroll
        for (int j = 0; j < 8; j++) {
            const int col = j * 16 + c;
            ABFrag b;
            *(uint4*)b.u = *(const uint4*)&ldsW[col * 128 + (kd ^ swz)];
            acc[j] = __builtin_amdgcn_mfma_f32_16x16x32_bf16(a.v, b.v, acc[j], 0, 0, 0);
        }
    }

    sl += __shfl_xor(sl, 16); sl += __shfl_xor(sl, 32);
    sr += __shfl_xor(sr, 16); sr += __shfl_xor(sr, 32);
    if (rv && kg == 0) { el[bm + myrow] = sl; er[bm + myrow] = sr; }

    __syncthreads();                             // done with W^T; reuse as scratch
    float* sc = (float*)ldsW + w * 2048;
#pragma unroll
    for (int j = 0; j < 8; j++)
#pragma unroll
        for (int r = 0; r < 4; r++)
            sc[(kg * 4 + r) * 128 + j * 16 + c] = acc[j][r];
    __syncthreads();
#pragma unroll
    for (int m = 0; m < 16; m++) {
        float2 p = *(const float2*)&sc[m * 128 + 2 * l];
        int orow = bm + w * 16 + m;
        if (orow < M) Whh[(size_t)orow * 64 + l] = cvtpk_bf2(p.x, p.y);
    }

    // ---- piggybacked scatter tail (blocks 0..NB-1 only) ----
    if (blockIdx.x < NB) {
        if (tid == 0) det = 0;
        for (int b = tid; b < nbuk; b += 512) cur[b] = 0;
        __syncthreads();
        {
            const unsigned* eu = (const unsigned*)EI;
            int nz = 0;
            for (int i = tid; i < 1024; i += 512)
                if (eu[2 * i + 1] != 0u) nz++;
            if (nz) atomicAdd(&det, 1);
        }
        __syncthreads();
        const int is64 = (det == 0);
        const int bid = blockIdx.x;
        int chunk = (E + NB - 1) / NB;
        int start = bid * chunk;
        int end = min(start + chunk, E);
        for (int i = start + tid; i < end; i += 512) {
            int s = edge_at(EI, i, is64);
            int d = edge_at(EI, E + i, is64);
            int b = s >> BUCK_SH;
            int pos = T[b] + Cx[b * NB + bid] + atomicAdd(&cur[b], 1);
            entries[pos] = ((uint32_t)(s & 127) << 17) | (uint32_t)d;
        }
    }
}

// ---------------------------------------------------------------------------
// bucket: one block per bucket — in-LDS counting sort, coalesced CSR output.
// ---------------------------------------------------------------------------
__global__ __launch_bounds__(256) void bucket_kernel(const uint32_t* __restrict__ entries,
                                                     const int* __restrict__ T,
                                                     int E, int N, int nbuk,
                                                     int* __restrict__ offsets,
                                                     int* __restrict__ edge_dst) {
    __shared__ uint32_t ent[CAP];
    __shared__ int outD[CAP];
    __shared__ int cnt[128], pre[128], cur[128];
    __shared__ int wt4[2];
    const int b = blockIdx.x;
    const int tid = threadIdx.x;
    const int base = T[b];
    const int cend = (b + 1 < nbuk) ? T[b + 1] : E;
    int count = cend - base;
    if (count > CAP) count = CAP;

    if (tid < 128) { cnt[tid] = 0; cur[tid] = 0; }
    __syncthreads();
    for (int k = tid; k < count; k += 256) {
        uint32_t e = entries[base + k];
        ent[k] = e;
        atomicAdd(&cnt[e >> 17], 1);
    }
    __syncthreads();
    {
        const int lane = tid & 63, w = tid >> 6;
        int c = (tid < 128) ? cnt[tid] : 0;
        int incl = c;
#pragma unroll
        for (int o = 1; o < 64; o <<= 1) {
            int v = __shfl_up(incl, o);
            if (lane >= o) incl += v;
        }
        if (w == 0 && lane == 63) wt4[0] = incl;
        __syncthreads();
        if (tid < 128) pre[tid] = ((w == 1) ? wt4[0] : 0) + incl - c;
        __syncthreads();
    }
    const int node0 = b << BUCK_SH;
    const int nnode = min(128, N - node0);
    if (tid < nnode) offsets[node0 + tid] = base + pre[tid];
    if (b == nbuk - 1 && tid == 0) offsets[N] = E;
    for (int k = tid; k < count; k += 256) {
        uint32_t e = ent[k];
        int sl = e >> 17;
        int p = pre[sl] + atomicAdd(&cur[sl], 1);
        outD[p] = (int)(e & 0x1FFFFu);
    }
    __syncthreads();
    for (int k = tid; k < count; k += 256)
        edge_dst[base + k] = outD[k];
}

// ---------------------------------------------------------------------------
// node: single-pass register softmax + PV, 4-deep gather (best measured).
// ---------------------------------------------------------------------------
__global__ __launch_bounds__(256) void node_kernel(const int* __restrict__ offsets,
                                                   const int* __restrict__ edge_dst,
                                                   const float* __restrict__ el,
                                                   const float* __restrict__ er,
                                                   const uint32_t* __restrict__ WhH,
                                                   float* __restrict__ out, int N) {
    int node = blockIdx.x * 4 + (threadIdx.x >> 6);
    int lane = threadIdx.x & 63;
    if (node >= N) return;
    int s0  = offsets[node];
    int deg = offsets[node + 1] - s0;
    float eli = el[node];

    if (deg <= 64) {
        int dj = 0;
        float e = -3.402823466e38f;
        if (lane < deg) {
            dj = edge_dst[s0 + lane];
            float t = eli + er[dj];
            e = t > 0.f ? t : ALPHA_SLOPE * t;
        }
        float m = e;
#pragma unroll
        for (int o = 32; o > 0; o >>= 1) m = fmaxf(m, __shfl_xor(m, o));
        float ex = (lane < deg) ? expf(e - m) : 0.f;
        float ssum = ex;
#pragma unroll
        for (int o = 32; o > 0; o >>= 1) ssum += __shfl_xor(ssum, o);
        float p = ex / (ssum + 1e-9f);

        const int g = lane >> 4, q = lane & 15;
        float a0 = 0.f, a1 = 0.f, a2 = 0.f, a3 = 0.f;
        float a4 = 0.f, a5 = 0.f, a6 = 0.f, a7 = 0.f;
        int rounds = (deg + 3) >> 2;
        int r = 0;
        for (; r + 4 <= rounds; r += 4) {
            int i0 = (r << 2) + g, i1 = i0 + 4, i2 = i0 + 8, i3 = i0 + 12;
            float p0 = __shfl(p, i0), p1 = __shfl(p, i1);
            float p2 = __shfl(p, i2), p3 = __shfl(p, i3);
            int   e0 = __shfl(dj, i0), e1 = __shfl(dj, i1);
            int   e2 = __shfl(dj, i2), e3 = __shfl(dj, i3);
            uint4 w0 = *(const uint4*)&WhH[(size_t)e0 * 64 + q * 4];
            uint4 w1 = *(const uint4*)&WhH[(size_t)e1 * 64 + q * 4];
            uint4 w2 = *(const uint4*)&WhH[(size_t)e2 * 64 + q * 4];
            uint4 w3 = *(const uint4*)&WhH[(size_t)e3 * 64 + q * 4];
            a0 = fmaf(p0, blo(w0.x), a0); a1 = fmaf(p0, bhi(w0.x), a1);
            a2 = fmaf(p0, blo(w0.y), a2); a3 = fmaf(p0, bhi(w0.y), a3);
            a4 = fmaf(p0, blo(w0.z), a4); a5 = fmaf(p0, bhi(w0.z), a5);
            a6 = fmaf(p0, blo(w0.w), a6); a7 = fmaf(p0, bhi(w0.w), a7);
            a0 = fmaf(p1, blo(w1.x), a0); a1 = fmaf(p1, bhi(w1.x), a1);
            a2 = fmaf(p1, blo(w1.y), a2); a3 = fmaf(p1, bhi(w1.y), a3);
            a4 = fmaf(p1, blo(w1.z), a4); a5 = fmaf(p1, bhi(w1.z), a5);
            a6 = fmaf(p1, blo(w1.w), a6); a7 = fmaf(p1, bhi(w1.w), a7);
            a0 = fmaf(p2, blo(w2.x), a0); a1 = fmaf(p2, bhi(w2.x), a1);
            a2 = fmaf(p2, blo(w2.y), a2); a3 = fmaf(p2, bhi(w2.y), a3);
            a4 = fmaf(p2, blo(w2.z), a4); a5 = fmaf(p2, bhi(w2.z), a5);
            a6 = fmaf(p2, blo(w2.w), a6); a7 = fmaf(p2, bhi(w2.w), a7);
            a0 = fmaf(p3, blo(w3.x), a0); a1 = fmaf(p3, bhi(w3.x), a1);
            a2 = fmaf(p3, blo(w3.y), a2); a3 = fmaf(p3, bhi(w3.y), a3);
            a4 = fmaf(p3, blo(w3.z), a4); a5 = fmaf(p3, bhi(w3.z), a5);
            a6 = fmaf(p3, blo(w3.w), a6); a7 = fmaf(p3, bhi(w3.w), a7);
        }
        for (; r + 2 <= rounds; r += 2) {
            int i0 = (r << 2) + g, i1 = i0 + 4;
            float p0 = __shfl(p, i0), p1 = __shfl(p, i1);
            int   e0 = __shfl(dj, i0), e1 = __shfl(dj, i1);
            uint4 w0 = *(const uint4*)&WhH[(size_t)e0 * 64 + q * 4];
            uint4 w1 = *(const uint4*)&WhH[(size_t)e1 * 64 + q * 4];
            a0 = fmaf(p0, blo(w0.x), a0); a1 = fmaf(p0, bhi(w0.x), a1);
            a2 = fmaf(p0, blo(w0.y), a2); a3 = fmaf(p0, bhi(w0.y), a3);
            a4 = fmaf(p0, blo(w0.z), a4); a5 = fmaf(p0, bhi(w0.z), a5);
            a6 = fmaf(p0, blo(w0.w), a6); a7 = fmaf(p0, bhi(w0.w), a7);
            a0 = fmaf(p1, blo(w1.x), a0); a1 = fmaf(p1, bhi(w1.x), a1);
            a2 = fmaf(p1, blo(w1.y), a2); a3 = fmaf(p1, bhi(w1.y), a3);
            a4 = fmaf(p1, blo(w1.z), a4); a5 = fmaf(p1, bhi(w1.z), a5);
            a6 = fmaf(p1, blo(w1.w), a6); a7 = fmaf(p1, bhi(w1.w), a7);
        }
        if (r < rounds) {
            int i0 = (r << 2) + g;
            float p0 = __shfl(p, i0);
            int   e0 = __shfl(dj, i0);
            uint4 w0 = *(const uint4*)&WhH[(size_t)e0 * 64 + q * 4];
            a0 = fmaf(p0, blo(w0.x), a0); a1 = fmaf(p0, bhi(w0.x), a1);
            a2 = fmaf(p0, blo(w0.y), a2); a3 = fmaf(p0, bhi(w0.y), a3);
            a4 = fmaf(p0, blo(w0.z), a4); a5 = fmaf(p0, bhi(w0.z), a5);
            a6 = fmaf(p0, blo(w0.w), a6); a7 = fmaf(p0, bhi(w0.w), a7);
        }
#pragma unroll
        for (int o = 16; o <= 32; o <<= 1) {
            a0 += __shfl_xor(a0, o); a1 += __shfl_xor(a1, o);
            a2 += __shfl_xor(a2, o); a3 += __shfl_xor(a3, o);
            a4 += __shfl_xor(a4, o); a5 += __shfl_xor(a5, o);
            a6 += __shfl_xor(a6, o); a7 += __shfl_xor(a7, o);
        }
        if (g == 0) {
            float4 o0 = make_float4(fmaxf(a0, 0.f), fmaxf(a1, 0.f),
                                    fmaxf(a2, 0.f), fmaxf(a3, 0.f));
            float4 o1 = make_float4(fmaxf(a4, 0.f), fmaxf(a5, 0.f),
                                    fmaxf(a6, 0.f), fmaxf(a7, 0.f));
            float* op = out + (size_t)node * OUT_F + q * 8;
            *(float4*)op = o0;
            *(float4*)(op + 4) = o1;
        }
        return;
    }

    // slow path (deg > 64)
    float m = -3.402823466e38f;
    for (int j = lane; j < deg; j += 64) {
        float e = eli + er[edge_dst[s0 + j]];
        e = e > 0.f ? e : ALPHA_SLOPE * e;
        m = fmaxf(m, e);
    }
#pragma unroll
    for (int o = 32; o > 0; o >>= 1) m = fmaxf(m, __shfl_xor(m, o));

    float ssum = 0.f;
    for (int j = lane; j < deg; j += 64) {
        float e = eli + er[edge_dst[s0 + j]];
        e = e > 0.f ? e : ALPHA_SLOPE * e;
        ssum += expf(e - m);
    }
#pragma unroll
    for (int o = 32; o > 0; o >>= 1) ssum += __shfl_xor(ssum, o);
    float inv = 1.f / (ssum + 1e-9f);

    float acc0 = 0.f, acc1 = 0.f;
    for (int base = 0; base < deg; base += 64) {
        int j = base + lane;
        float p = 0.f;
        int d = 0;
        if (j < deg) {
            d = edge_dst[s0 + j];
            float e = eli + er[d];
            e = e > 0.f ? e : ALPHA_SLOPE * e;
            p = expf(e - m) * inv;
        }
        int cnt = min(64, deg - base);
        int t = 0;
        for (; t + 8 <= cnt; t += 8) {
            float b0 = RL_F(p, t + 0), b1 = RL_F(p, t + 1);
            float b2 = RL_F(p, t + 2), b3 = RL_F(p, t + 3);
            float b4 = RL_F(p, t + 4), b5 = RL_F(p, t + 5);
            float b6 = RL_F(p, t + 6), b7 = RL_F(p, t + 7);
            int   d0 = RL_I(d, t + 0), d1 = RL_I(d, t + 1);
            int   d2 = RL_I(d, t + 2), d3 = RL_I(d, t + 3);
            int   d4 = RL_I(d, t + 4), d5 = RL_I(d, t + 5);
            int   d6 = RL_I(d, t + 6), d7 = RL_I(d, t + 7);
            uint32_t w0 = WhH[(size_t)d0 * 64 + lane];
            uint32_t w1 = WhH[(size_t)d1 * 64 + lane];
            uint32_t w2 = WhH[(size_t)d2 * 64 + lane];
            uint32_t w3 = WhH[(size_t)d3 * 64 + lane];
            uint32_t w4 = WhH[(size_t)d4 * 64 + lane];
            uint32_t w5 = WhH[(size_t)d5 * 64 + lane];
            uint32_t w6 = WhH[(size_t)d6 * 64 + lane];
            uint32_t w7 = WhH[(size_t)d7 * 64 + lane];
            acc0 = fmaf(b0, blo(w0), acc0); acc1 = fmaf(b0, bhi(w0), acc1);
            acc0 = fmaf(b1, blo(w1), acc0); acc1 = fmaf(b1, bhi(w1), acc1);
            acc0 = fmaf(b2, blo(w2), acc0); acc1 = fmaf(b2, bhi(w2), acc1);
            acc0 = fmaf(b3, blo(w3), acc0); acc1 = fmaf(b3, bhi(w3), acc1);
            acc0 = fmaf(b4, blo(w4), acc0); acc1 = fmaf(b4, bhi(w4), acc1);
            acc0 = fmaf(b5, blo(w5), acc0); acc1 = fmaf(b5, bhi(w5), acc1);
            acc0 = fmaf(b6, blo(w6), acc0); acc1 = fmaf(b6, bhi(w6), acc1);
            acc0 = fmaf(b7, blo(w7), acc0); acc1 = fmaf(b7, bhi(w7), acc1);
        }
        for (; t < cnt; ++t) {
            float a = RL_F(p, t);
            int  dd = RL_I(d, t);
            uint32_t wv = WhH[(size_t)dd * 64 + lane];
            acc0 = fmaf(a, blo(wv), acc0);
            acc1 = fmaf(a, bhi(wv), acc1);
        }
    }
    out[(size_t)node * OUT_F + 2 * lane]     = fmaxf(acc0, 0.f);
    out[(size_t)node * OUT_F + 2 * lane + 1] = fmaxf(acc1, 0.f);
}

// ---------------------------------------------------------------------------
extern "C" void kernel_launch(void* const* d_in, const int* in_sizes, int n_in,
                              void* d_out, int out_size, void* d_ws, size_t ws_size,
                              hipStream_t stream) {
    (void)n_in; (void)out_size; (void)ws_size;
    const float* X  = (const float*)d_in[0];
    const void*  EI = d_in[1];
    const float* W  = (const float*)d_in[2];
    const float* aL = (const float*)d_in[3];
    const float* aR = (const float*)d_in[4];
    float* out = (float*)d_out;
    const int N = in_sizes[0] / IN_F;
    const int E = in_sizes[1] / 2;
    const int nbuk = (N + 127) >> BUCK_SH;       // 782 for N=100000
    const int GB = (N + 127) / 128;              // gemm blocks (>= NB for N=100000)

    char* ws = (char*)d_ws;
    float*    waL      = (float*)(ws + 256);            // 256 f32
    float*    waR      = waL + 256;                     // 256 f32
    uint32_t* WtH      = (uint32_t*)(waR + 256);        // 16384 dwords (64 KB)
    uint32_t* Whh      = WtH + 16384;                   // N*64 dwords
    float*    el       = (float*)(Whh + (size_t)N * 64);
    float*    er       = el + N;                        // N
    int*      T        = (int*)(er + N);                // nbuk (pad 1024)
    int*      C        = T + 1024;                      // nbuk*NB
    int*      Cx       = C + (size_t)nbuk * NB;         // nbuk*NB
    int*      offsets  = Cx + (size_t)nbuk * NB;        // N+1
    uint32_t* entries  = (uint32_t*)(offsets + (N + 1)); // E
    int*      edge_dst = (int*)(entries + E);           // E

    prep_hist_kernel<<<65 + NB, 256, 0, stream>>>(W, aL, aR, EI, E, nbuk,
                                                  WtH, waL, waR, C);
    scan1_kernel<<<nbuk, 256, 0, stream>>>(C, Cx, T, nbuk * NB);
    scan2_kernel<<<1, 256, 0, stream>>>(T, nbuk);
    gemm_scatter_kernel<<<GB, 512, 0, stream>>>(X, WtH, waL, waR, Whh, el, er,
                                                N, EI, E, nbuk, Cx, T, entries);
    bucket_kernel<<<nbuk, 256, 0, stream>>>(entries, T, E, N, nbuk, offsets, edge_dst);
    node_kernel<<<(N + 3) / 4, 256, 0, stream>>>(offsets, edge_dst, el, er, Whh, out, N);
}